// Round 18
// baseline (69.422 us; speedup 1.0000x reference)
//
#include <hip/hip_runtime.h>
#include <hip/hip_bf16.h>

#define NV 50000

// ws layout:
//   [0, 32768)        AhTs packed f16x2, B-frag quad order (STD d order): [eq][od][r]
//   [32768, 33792)    rbar f32 [256] (std)
//   [33792, 34304)    wvh  packed f16x2 [8 i][4 h][4 jp] (W_V)
//   [34816, +6.4MB)   xh   packed f16x2 [NV][32]         (x converted)

typedef _Float16 h2_t __attribute__((ext_vector_type(2)));
typedef _Float16 f16x4 __attribute__((ext_vector_type(4)));
typedef _Float16 f16x8 __attribute__((ext_vector_type(8)));
typedef float f32x4 __attribute__((ext_vector_type(4)));

#if defined(__has_builtin)
#if __has_builtin(__builtin_amdgcn_fdot2)
#define HAVE_FDOT2 1
#endif
#endif

__device__ __forceinline__ float fdot2f(h2_t a, h2_t b, float c) {
#ifdef HAVE_FDOT2
  return __builtin_amdgcn_fdot2(a, b, c, false);
#else
  return fmaf((float)a.x, (float)b.x, fmaf((float)a.y, (float)b.y, c));
#endif
}
__device__ __forceinline__ h2_t u2h(unsigned u) {
  union { unsigned u; h2_t h; } c; c.u = u; return c.h;
}
__device__ __forceinline__ unsigned pk2(float a, float b) {
  auto v = __builtin_amdgcn_cvt_pkrtz(a, b);
  union { decltype(v) h; unsigned u; } c; c.h = v; return c.u;
}
__device__ __forceinline__ f16x8 u4h8(uint4 u) {
  union { uint4 u; f16x8 h; } c; c.u = u; return c.h;
}
__device__ __forceinline__ f16x4 u2h4(uint2 u) {
  union { uint2 u; f16x4 h; } c; c.u = u; return c.h;
}
// IR-level memory clobber + HW LDS drain + scheduler pin (rule #18)
__device__ __forceinline__ void lds_fence() {
  asm volatile("s_waitcnt lgkmcnt(0)" ::: "memory");
  __builtin_amdgcn_sched_barrier(0);
}

// setup (blocks 0..31, STD order) + xconv (blocks 32..) fused
__global__ void prep_kernel(const float* __restrict__ WQ, const float* __restrict__ WQb,
                            const float* __restrict__ WK,
                            const float* __restrict__ bases, const float* __restrict__ coeffs,
                            const float* __restrict__ x,
                            unsigned* __restrict__ AhTs, float* __restrict__ rbar,
                            unsigned* __restrict__ wvh, unsigned* __restrict__ xh) {
  if (blockIdx.x < 32) {
    int ep = blockIdx.x;      // 0..31 (e-pair)
    int od = threadIdx.x;     // 0..255 : h*64+d
    int h = od >> 6, d = od & 63;
    int e0 = ep * 2;
    float s0 = 0.f, s1 = 0.f;
#pragma unroll 4
    for (int k = 0; k < 64; ++k) {
      float wk = WK[(h * 64 + k) * 64 + d];
      s0 += WQ[(h * 64 + k) * 64 + e0] * wk;
      s1 += WQ[(h * 64 + k) * 64 + e0 + 1] * wk;
    }
    AhTs[((ep >> 2) * 256 + od) * 4 + (ep & 3)] = pk2(s0 * 0.125f, s1 * 0.125f);
    if (ep == 0) {
      float r = 0.f;
      for (int k = 0; k < 64; ++k) r += WQb[h * 64 + k] * WK[(h * 64 + k) * 64 + d];
      rbar[od] = r * 0.125f;
      if (od < 128) {   // wvh[i][h][jp]
        int i = od >> 4, hh = (od >> 2) & 3, jp = od & 3;
        float w0 = 0.f, w1 = 0.f;
        for (int b = 0; b < 6; ++b) {
          w0 += coeffs[hh * 6 + b] * bases[b * 64 + i * 8 + 2 * jp];
          w1 += coeffs[hh * 6 + b] * bases[b * 64 + i * 8 + 2 * jp + 1];
        }
        wvh[od] = pk2(w0, w1);
      }
    }
  } else {
    int idx = (blockIdx.x - 32) * 256 + threadIdx.x;
    if (idx < NV * 8) {
      float4 a = ((const float4*)x)[idx * 2];
      float4 b = ((const float4*)x)[idx * 2 + 1];
      uint4 o;
      o.x = pk2(a.x, a.y);
      o.y = pk2(a.z, a.w);
      o.z = pk2(b.x, b.y);
      o.w = pk2(b.z, b.w);
      ((uint4*)xh)[idx] = o;
    }
  }
}

// ---------------- attention: R15 config extended to 1 wave = 4 vertices (block = 16):
//  q~ ONE MFMA pass now fills ALL 16 C-rows (16 distinct vertices, no predication) —
//  front-half cost per vertex halves. Back half = proven va->vb chain extended to 4 stages
//  with identical fence/epoch hazard structure. P(vb..vd) packed f16 at load; vc/vd loads
//  issued post-q~-peak / mid-chain (R14 no-spill pattern). Plain P loads + nt out stores. ----------------
__global__ __launch_bounds__(256, 4) void attn_kernel(
    const unsigned* __restrict__ xh, const int* __restrict__ nbr,
    const float* __restrict__ P, const unsigned* __restrict__ AhTs,
    const float* __restrict__ rbar, const unsigned* __restrict__ wvh,
    float* __restrict__ out) {
  __shared__ __align__(16) _Float16 TA[4][1152];     // 9 KB  Ph tile (rotates va..vd)   [16m][72]
  __shared__ __align__(16) _Float16 TB[4][1152];     // 9 KB  Xd tile (rotates)          [16m][72]
  __shared__ __align__(16) _Float16 TC[4][1152];     // 9 KB  Ftr tile (rotates)         [16m][72]
  __shared__ __align__(16) _Float16 q16[16][256];    // 8 KB  [vi 0..15][h*64+d]; row w re-used as g16
  // total 35 KB (x4 blocks = 140 KB)

  const int t = threadIdx.x;
  const int w = t >> 6, lane = t & 63;
  const int v0 = blockIdx.x * 16;
  const int va = v0 + w, vb = v0 + 4 + w, vc = v0 + 8 + w, vd = v0 + 12 + w;
  const int c_ep = lane >> 3, i_ep = lane & 7;
  const int m_ = lane & 15, dg = lane >> 4;      // f'/scores lane decomposition
  const char* xhb = (const char*)xh;
  _Float16* g16w = &q16[w][0];                   // alias: 4 h x 64 d, stride 64 (row w only)

  // P-staging lane map (slab s: m = s*4+pm, f16 offset po = (lane&15)*4)
  const int pm = lane >> 4;
  const int po = ((lane & 15) >> 1) * 8 + 4 * (lane & 1);
  const int rl = lane & 15, kg = lane >> 4;
  const int hb = (lane & 15) & 3;

  // ---- neighbor indices (all 4 vertices; 8 regs) ----
  int nbA0 = nbr[(size_t)va * 16 + (lane >> 3)];
  int nbA1 = nbr[(size_t)va * 16 + 8 + (lane >> 3)];
  int nbB0 = nbr[(size_t)vb * 16 + (lane >> 3)];
  int nbB1 = nbr[(size_t)vb * 16 + 8 + (lane >> 3)];
  int nbC0 = nbr[(size_t)vc * 16 + (lane >> 3)];
  int nbC1 = nbr[(size_t)vc * 16 + 8 + (lane >> 3)];
  int nbD0 = nbr[(size_t)vd * 16 + (lane >> 3)];
  int nbD1 = nbr[(size_t)vd * 16 + 8 + (lane >> 3)];

  // ---- helpers ----
  auto loadPackP = [&](const float* base, uint2& q0, uint2& q1, uint2& q2, uint2& q3) {
    const f32x4* Pg = (const f32x4*)base;
    f32x4 r0 = Pg[lane], r1 = Pg[64 + lane], r2 = Pg[128 + lane], r3 = Pg[192 + lane];
    q0.x = pk2(r0[0], r0[1]); q0.y = pk2(r0[2], r0[3]);
    q1.x = pk2(r1[0], r1[1]); q1.y = pk2(r1[2], r1[3]);
    q2.x = pk2(r2[0], r2[1]); q2.y = pk2(r2[2], r2[3]);
    q3.x = pk2(r3[0], r3[1]); q3.y = pk2(r3[2], r3[3]);
  };
  auto stagePX = [&](uint2 q0, uint2 q1, uint2 q2, uint2 q3, uint4 x0, uint4 x1) {
    *(uint2*)&TA[w][(0 + pm) * 72 + po]  = q0;
    *(uint2*)&TA[w][(4 + pm) * 72 + po]  = q1;
    *(uint2*)&TA[w][(8 + pm) * 72 + po]  = q2;
    *(uint2*)&TA[w][(12 + pm) * 72 + po] = q3;
    *(uint4*)&TB[w][(lane >> 3) * 72 + (lane & 7) * 8] = x0;
    *(uint4*)&TB[w][((lane >> 3) + 8) * 72 + (lane & 7) * 8] = x1;
  };
  auto writeTC = [&](uint4 A0, uint4 A1) {
    *(uint4*)&TC[w][m_ * 72 + dg * 8] = A0;
    *(uint4*)&TC[w][m_ * 72 + 32 + dg * 8] = A1;
  };
  // f' + scores + in-reg softmax (reads TA/TB; bq frags passed in)
  auto fsm = [&](f16x8 bq0, f16x8 bq1, uint4& A0, uint4& A1) -> f16x4 {
    uint4 Plo = *(const uint4*)&TA[w][m_ * 72 + dg * 8];           // P[m_][o=dg][j]
    uint4 Phi = *(const uint4*)&TA[w][m_ * 72 + (dg + 4) * 8];     // P[m_][o=dg+4][j]
    float fr0[8], fr1[8];
    __builtin_amdgcn_s_setprio(1);
#pragma unroll
    for (int c = 0; c < 8; ++c) {
      uint4 Xu = *(const uint4*)&TB[w][m_ * 72 + c * 8];           // X[m_][c][j]
      fr0[c] = fdot2f(u2h(Plo.x), u2h(Xu.x),
               fdot2f(u2h(Plo.y), u2h(Xu.y),
               fdot2f(u2h(Plo.z), u2h(Xu.z),
               fdot2f(u2h(Plo.w), u2h(Xu.w), 0.f))));
      fr1[c] = fdot2f(u2h(Phi.x), u2h(Xu.x),
               fdot2f(u2h(Phi.y), u2h(Xu.y),
               fdot2f(u2h(Phi.z), u2h(Xu.z),
               fdot2f(u2h(Phi.w), u2h(Xu.w), 0.f))));
    }
    __builtin_amdgcn_s_setprio(0);
    A0.x = pk2(fr0[0], fr0[1]); A0.y = pk2(fr0[2], fr0[3]);
    A0.z = pk2(fr0[4], fr0[5]); A0.w = pk2(fr0[6], fr0[7]);
    A1.x = pk2(fr1[0], fr1[1]); A1.y = pk2(fr1[2], fr1[3]);
    A1.z = pk2(fr1[4], fr1[5]); A1.w = pk2(fr1[6], fr1[7]);
    f32x4 sac = (f32x4){0.f, 0.f, 0.f, 0.f};
    sac = __builtin_amdgcn_mfma_f32_16x16x32_f16(u4h8(A0), bq0, sac, 0, 0, 0);
    sac = __builtin_amdgcn_mfma_f32_16x16x32_f16(u4h8(A1), bq1, sac, 0, 0, 0);
    float e0 = __expf(sac[0]), e1 = __expf(sac[1]);
    float e2 = __expf(sac[2]), e3 = __expf(sac[3]);
    float pp = (e0 + e1) + (e2 + e3);
    pp += __shfl_xor(pp, 16);
    pp += __shfl_xor(pp, 32);
    float is = __builtin_amdgcn_rcpf(pp);
    uint2 eu;
    eu.x = pk2(e0 * is, e1 * is);
    eu.y = pk2(e2 * is, e3 * is);
    return u2h4(eu);
  };
  auto gphase = [&](f16x4 eb) {
    __builtin_amdgcn_s_setprio(1);
#pragma unroll
    for (int b2i = 0; b2i < 4; ++b2i) {
      f16x4 ga;
#pragma unroll
      for (int tt = 0; tt < 4; ++tt)
        ga[tt] = TC[w][(kg * 4 + tt) * 72 + b2i * 16 + rl];   // A[i=rl][k=kg*4+tt]
      f32x4 zg = (f32x4){0.f, 0.f, 0.f, 0.f};
      f32x4 gacc = __builtin_amdgcn_mfma_f32_16x16x16f16(ga, eb, zg, 0, 0, 0);
      if (rl < 4) {
        uint2 gv;
        gv.x = pk2(gacc[0], gacc[1]);
        gv.y = pk2(gacc[2], gacc[3]);
        *(uint2*)&g16w[rl * 64 + b2i * 16 + kg * 4] = gv;
      }
    }
    __builtin_amdgcn_s_setprio(0);
  };

  // ---- X gathers va+vb; P va (f32) + vb (packed) ----
  uint4 xA0 = *(const uint4*)(xhb + (size_t)nbA0 * 128 + (lane & 7) * 16);
  uint4 xA1 = *(const uint4*)(xhb + (size_t)nbA1 * 128 + (lane & 7) * 16);
  uint4 xB0 = *(const uint4*)(xhb + (size_t)nbB0 * 128 + (lane & 7) * 16);
  uint4 xB1 = *(const uint4*)(xhb + (size_t)nbB1 * 128 + (lane & 7) * 16);
  uint2 pb0, pb1, pb2, pb3;
  loadPackP(P + (size_t)vb * 1024, pb0, pb1, pb2, pb3);
  {
    const f32x4* PgA = (const f32x4*)(P + (size_t)va * 1024);
    f32x4 a0 = PgA[lane], a1 = PgA[64 + lane], a2 = PgA[128 + lane], a3 = PgA[192 + lane];
    uint2 u0, u1, u2, u3;
    u0.x = pk2(a0[0], a0[1]); u0.y = pk2(a0[2], a0[3]);
    u1.x = pk2(a1[0], a1[1]); u1.y = pk2(a1[2], a1[3]);
    u2.x = pk2(a2[0], a2[1]); u2.y = pk2(a2[2], a2[3]);
    u3.x = pk2(a3[0], a3[1]); u3.y = pk2(a3[2], a3[3]);
    stagePX(u0, u1, u2, u3, xA0, xA1);
  }

  // ---- rbar ----
  float rbq[4];
#pragma unroll
  for (int tt = 0; tt < 4; ++tt) rbq[tt] = rbar[w * 64 + tt * 16 + (lane & 15)];

  // ---- q~ via ONE MFMA pass: A rows i = lane&15 = vertex v0+i (ALL 16 distinct) ----
  {
    const int od0 = w * 64;
    uint4 bu[2][4];
#pragma unroll
    for (int s = 0; s < 2; ++s)
#pragma unroll
      for (int tt = 0; tt < 4; ++tt)
        bu[s][tt] = *(const uint4*)&AhTs[((s * 4 + (lane >> 4)) * 256 + od0 + tt * 16 + (lane & 15)) * 4];

    const uint4* xr = (const uint4*)(xh + (size_t)(v0 + (lane & 15)) * 32);
    f16x8 af0 = u4h8(xr[(lane >> 4)]);       // K-step 0: e 0..31 (octet kg)
    f16x8 af1 = u4h8(xr[4 + (lane >> 4)]);   // K-step 1: e 32..63
    f32x4 acc[4];
#pragma unroll
    for (int tt = 0; tt < 4; ++tt) acc[tt] = (f32x4){0.f, 0.f, 0.f, 0.f};
    __builtin_amdgcn_s_setprio(1);
#pragma unroll
    for (int tt = 0; tt < 4; ++tt)
#pragma unroll
      for (int s = 0; s < 2; ++s)
        acc[tt] = __builtin_amdgcn_mfma_f32_16x16x32_f16(s ? af1 : af0, u4h8(bu[s][tt]),
                                                         acc[tt], 0, 0, 0);
    __builtin_amdgcn_s_setprio(0);
    // C: col = lane&15, row = (lane>>4)*4 + reg; rows 0..15 = v0..v0+15 (all lanes write)
#pragma unroll
    for (int tt = 0; tt < 4; ++tt)
#pragma unroll
      for (int reg = 0; reg < 4; ++reg)
        q16[(lane >> 4) * 4 + reg][od0 + tt * 16 + (lane & 15)] =
            (_Float16)(acc[tt][reg] + rbq[tt]);
  }

  // ---- vc/vd P issued AFTER the q~ register peak (R14 pattern) ----
  __builtin_amdgcn_sched_barrier(0);
  uint2 pc0, pc1, pc2, pc3, pd0, pd1, pd2, pd3;
  loadPackP(P + (size_t)vc * 1024, pc0, pc1, pc2, pc3);
  loadPackP(P + (size_t)vd * 1024, pd0, pd1, pd2, pd3);
  __syncthreads();   // drains VMEM + LDS (Ph/Xd(va), q16); publishes q16

  // ---- va B-frags (row w dies after these reads -> g16 alias) ----
  f16x8 bqa0 = u4h8(*(const uint4*)&q16[w][hb * 64 + dg * 8]);
  f16x8 bqa1 = u4h8(*(const uint4*)&q16[w][hb * 64 + 32 + dg * 8]);

  // ================= va: f' + scores + softmax =================
  uint4 A0a, A1a;
  f16x4 eba = fsm(bqa0, bqa1, A0a, A1a);
  lds_fence();   // f'(va) reads + bqa retired -> TA/TB/TC/q16[w] writable

  // ---- epoch: TC<-A(va) ; stage vb ; issue X(vc) ----
  writeTC(A0a, A1a);
  stagePX(pb0, pb1, pb2, pb3, xB0, xB1);
  uint4 xC0 = *(const uint4*)(xhb + (size_t)nbC0 * 128 + (lane & 7) * 16);
  uint4 xC1 = *(const uint4*)(xhb + (size_t)nbC1 * 128 + (lane & 7) * 16);
  lds_fence();

  // ---- epoch: g(va) ; f'(vb) ----
  gphase(eba);
  uint4 A0b, A1b;
  f16x4 ebb;
  {
    f16x8 bqb0 = u4h8(*(const uint4*)&q16[4 + w][hb * 64 + dg * 8]);
    f16x8 bqb1 = u4h8(*(const uint4*)&q16[4 + w][hb * 64 + 32 + dg * 8]);
    ebb = fsm(bqb0, bqb1, A0b, A1b);
  }
  uint4 wq[4];
#pragma unroll
  for (int h = 0; h < 4; ++h) wq[h] = *(const uint4*)&wvh[i_ep * 16 + h * 4];
  lds_fence();

  // ---- epoch: epi(va) ; TC<-A(vb) ; stage vc ; issue X(vd) ----
#pragma unroll
  for (int h = 0; h < 4; ++h) {
    uint4 gq = *(const uint4*)&g16w[h * 64 + c_ep * 8];
    float oacc = fdot2f(u2h(wq[h].x), u2h(gq.x),
                 fdot2f(u2h(wq[h].y), u2h(gq.y),
                 fdot2f(u2h(wq[h].z), u2h(gq.z),
                 fdot2f(u2h(wq[h].w), u2h(gq.w), 0.f))));
    __builtin_nontemporal_store(oacc, &out[(size_t)va * 256 + h * 64 + lane]);
  }
  writeTC(A0b, A1b);
  stagePX(pc0, pc1, pc2, pc3, xC0, xC1);
  uint4 xD0 = *(const uint4*)(xhb + (size_t)nbD0 * 128 + (lane & 7) * 16);
  uint4 xD1 = *(const uint4*)(xhb + (size_t)nbD1 * 128 + (lane & 7) * 16);
  lds_fence();

  // ---- epoch: g(vb) ; f'(vc) ----
  gphase(ebb);
  uint4 A0c, A1c;
  f16x4 ebc;
  {
    f16x8 bqc0 = u4h8(*(const uint4*)&q16[8 + w][hb * 64 + dg * 8]);
    f16x8 bqc1 = u4h8(*(const uint4*)&q16[8 + w][hb * 64 + 32 + dg * 8]);
    ebc = fsm(bqc0, bqc1, A0c, A1c);
  }
  lds_fence();

  // ---- epoch: epi(vb) ; TC<-A(vc) ; stage vd ----
#pragma unroll
  for (int h = 0; h < 4; ++h) {
    uint4 gq = *(const uint4*)&g16w[h * 64 + c_ep * 8];
    float oacc = fdot2f(u2h(wq[h].x), u2h(gq.x),
                 fdot2f(u2h(wq[h].y), u2h(gq.y),
                 fdot2f(u2h(wq[h].z), u2h(gq.z),
                 fdot2f(u2h(wq[h].w), u2h(gq.w), 0.f))));
    __builtin_nontemporal_store(oacc, &out[(size_t)vb * 256 + h * 64 + lane]);
  }
  writeTC(A0c, A1c);
  stagePX(pd0, pd1, pd2, pd3, xD0, xD1);
  lds_fence();

  // ---- epoch: g(vc) ; f'(vd) ----
  gphase(ebc);
  uint4 A0d, A1d;
  f16x4 ebd;
  {
    f16x8 bqd0 = u4h8(*(const uint4*)&q16[12 + w][hb * 64 + dg * 8]);
    f16x8 bqd1 = u4h8(*(const uint4*)&q16[12 + w][hb * 64 + 32 + dg * 8]);
    ebd = fsm(bqd0, bqd1, A0d, A1d);
  }
  lds_fence();

  // ---- epoch: epi(vc) ; TC<-A(vd) ----
#pragma unroll
  for (int h = 0; h < 4; ++h) {
    uint4 gq = *(const uint4*)&g16w[h * 64 + c_ep * 8];
    float oacc = fdot2f(u2h(wq[h].x), u2h(gq.x),
                 fdot2f(u2h(wq[h].y), u2h(gq.y),
                 fdot2f(u2h(wq[h].z), u2h(gq.z),
                 fdot2f(u2h(wq[h].w), u2h(gq.w), 0.f))));
    __builtin_nontemporal_store(oacc, &out[(size_t)vc * 256 + h * 64 + lane]);
  }
  writeTC(A0d, A1d);
  lds_fence();

  // ---- epoch: g(vd) ----
  gphase(ebd);
  lds_fence();

  // ---- epi(vd) ----
#pragma unroll
  for (int h = 0; h < 4; ++h) {
    uint4 gq = *(const uint4*)&g16w[h * 64 + c_ep * 8];
    float oacc = fdot2f(u2h(wq[h].x), u2h(gq.x),
                 fdot2f(u2h(wq[h].y), u2h(gq.y),
                 fdot2f(u2h(wq[h].z), u2h(gq.z),
                 fdot2f(u2h(wq[h].w), u2h(gq.w), 0.f))));
    __builtin_nontemporal_store(oacc, &out[(size_t)vd * 256 + h * 64 + lane]);
  }
}

extern "C" void kernel_launch(void* const* d_in, const int* in_sizes, int n_in,
                              void* d_out, int out_size, void* d_ws, size_t ws_size,
                              hipStream_t stream) {
  const float* x      = (const float*)d_in[0];
  const int*   nbr    = (const int*)d_in[1];
  const float* P      = (const float*)d_in[2];
  // d_in[3] = rel_pos_u : unused by the reference
  const float* WQ     = (const float*)d_in[4];
  const float* WQb    = (const float*)d_in[5];
  const float* WK     = (const float*)d_in[6];
  // d_in[7] = W_K_b : softmax-invariant -> dropped
  const float* bases  = (const float*)d_in[8];
  const float* coeffs = (const float*)d_in[9];

  unsigned* AhTs = (unsigned*)d_ws;
  float* rbar   = (float*)((char*)d_ws + 32768);
  unsigned* wvh = (unsigned*)((char*)d_ws + 33792);
  unsigned* xh  = (unsigned*)((char*)d_ws + 34816);
  float* out    = (float*)d_out;

  hipLaunchKernelGGL(prep_kernel, dim3(32 + (NV * 8 + 255) / 256), dim3(256), 0, stream,
                     WQ, WQb, WK, bases, coeffs, x, AhTs, rbar, wvh, xh);
  hipLaunchKernelGGL(attn_kernel, dim3(NV / 16), dim3(256), 0, stream,
                     xh, nbr, P, AhTs, rbar, wvh, out);
}

// Round 19
// 65.176 us; speedup vs baseline: 1.0651x; 1.0651x over previous
//
#include <hip/hip_runtime.h>
#include <hip/hip_bf16.h>

#define NV 50000

// ws layout:
//   [0, 32768)        AhTs packed f16x2, B-frag quad order (STD d order): [eq][od][r]
//   [32768, 33792)    rbar f32 [256] (std)
//   [33792, 34304)    wvh  packed f16x2 [8 i][4 h][4 jp] (W_V)
//   [34816, +6.4MB)   xh   packed f16x2 [NV][32]         (x converted)

typedef _Float16 h2_t __attribute__((ext_vector_type(2)));
typedef _Float16 f16x4 __attribute__((ext_vector_type(4)));
typedef _Float16 f16x8 __attribute__((ext_vector_type(8)));
typedef float f32x4 __attribute__((ext_vector_type(4)));

#if defined(__has_builtin)
#if __has_builtin(__builtin_amdgcn_fdot2)
#define HAVE_FDOT2 1
#endif
#endif

__device__ __forceinline__ float fdot2f(h2_t a, h2_t b, float c) {
#ifdef HAVE_FDOT2
  return __builtin_amdgcn_fdot2(a, b, c, false);
#else
  return fmaf((float)a.x, (float)b.x, fmaf((float)a.y, (float)b.y, c));
#endif
}
__device__ __forceinline__ h2_t u2h(unsigned u) {
  union { unsigned u; h2_t h; } c; c.u = u; return c.h;
}
__device__ __forceinline__ unsigned pk2(float a, float b) {
  auto v = __builtin_amdgcn_cvt_pkrtz(a, b);
  union { decltype(v) h; unsigned u; } c; c.h = v; return c.u;
}
__device__ __forceinline__ f16x8 u4h8(uint4 u) {
  union { uint4 u; f16x8 h; } c; c.u = u; return c.h;
}
__device__ __forceinline__ f16x4 u2h4(uint2 u) {
  union { uint2 u; f16x4 h; } c; c.u = u; return c.h;
}
// IR-level memory clobber + HW LDS drain + scheduler pin (rule #18)
__device__ __forceinline__ void lds_fence() {
  asm volatile("s_waitcnt lgkmcnt(0)" ::: "memory");
  __builtin_amdgcn_sched_barrier(0);
}

// setup (blocks 0..31, STD order) + xconv (blocks 32..) fused
__global__ void prep_kernel(const float* __restrict__ WQ, const float* __restrict__ WQb,
                            const float* __restrict__ WK,
                            const float* __restrict__ bases, const float* __restrict__ coeffs,
                            const float* __restrict__ x,
                            unsigned* __restrict__ AhTs, float* __restrict__ rbar,
                            unsigned* __restrict__ wvh, unsigned* __restrict__ xh) {
  if (blockIdx.x < 32) {
    int ep = blockIdx.x;      // 0..31 (e-pair)
    int od = threadIdx.x;     // 0..255 : h*64+d
    int h = od >> 6, d = od & 63;
    int e0 = ep * 2;
    float s0 = 0.f, s1 = 0.f;
#pragma unroll 4
    for (int k = 0; k < 64; ++k) {
      float wk = WK[(h * 64 + k) * 64 + d];
      s0 += WQ[(h * 64 + k) * 64 + e0] * wk;
      s1 += WQ[(h * 64 + k) * 64 + e0 + 1] * wk;
    }
    AhTs[((ep >> 2) * 256 + od) * 4 + (ep & 3)] = pk2(s0 * 0.125f, s1 * 0.125f);
    if (ep == 0) {
      float r = 0.f;
      for (int k = 0; k < 64; ++k) r += WQb[h * 64 + k] * WK[(h * 64 + k) * 64 + d];
      rbar[od] = r * 0.125f;
      if (od < 128) {   // wvh[i][h][jp]
        int i = od >> 4, hh = (od >> 2) & 3, jp = od & 3;
        float w0 = 0.f, w1 = 0.f;
        for (int b = 0; b < 6; ++b) {
          w0 += coeffs[hh * 6 + b] * bases[b * 64 + i * 8 + 2 * jp];
          w1 += coeffs[hh * 6 + b] * bases[b * 64 + i * 8 + 2 * jp + 1];
        }
        wvh[od] = pk2(w0, w1);
      }
    }
  } else {
    int idx = (blockIdx.x - 32) * 256 + threadIdx.x;
    if (idx < NV * 8) {
      float4 a = ((const float4*)x)[idx * 2];
      float4 b = ((const float4*)x)[idx * 2 + 1];
      uint4 o;
      o.x = pk2(a.x, a.y);
      o.y = pk2(a.z, a.w);
      o.z = pk2(b.x, b.y);
      o.w = pk2(b.z, b.w);
      ((uint4*)xh)[idx] = o;
    }
  }
}

// ---------------- attention: FINAL = R15 configuration (best, 65.45us, reproduced 65.61):
//  2-vertex pipeline, fragment-direct f' (stride-72 tiles), one-pass q~ MFMA, in-reg softmax,
//  g via 16x16x16f16 MFMA, setprio on compute clusters, plain cached P loads, nt out stores,
//  __launch_bounds__(256,4). Bracketed optima: vertices/wave 1<2>4; blocks/CU 4>=5;
//  nt-load off>on (-7%); nt-store on>off (+4%); setprio on>off (+2.6%). ----------------
__global__ __launch_bounds__(256, 4) void attn_kernel(
    const unsigned* __restrict__ xh, const int* __restrict__ nbr,
    const float* __restrict__ P, const unsigned* __restrict__ AhTs,
    const float* __restrict__ rbar, const unsigned* __restrict__ wvh,
    float* __restrict__ out) {
  __shared__ __align__(16) _Float16 TA[4][1152];     // 9 KB  Ph(va) -> Ph(vb)      [16m][72]
  __shared__ __align__(16) _Float16 TB[4][1152];     // 9 KB  Xd(va) -> Xd(vb)      [16m][72]
  __shared__ __align__(16) _Float16 TC[4][1152];     // 9 KB  Ftr(va) -> Ftr(vb)    [16m][72]
  __shared__ __align__(16) _Float16 q16[8][256];     // 4 KB  [vi][h*64+d]; row w re-used as g16 (stride 64)
  // total 31 KB

  const int t = threadIdx.x;
  const int w = t >> 6, lane = t & 63;
  const int v0 = blockIdx.x * 8;
  const int va = v0 + w, vb = v0 + 4 + w;
  const int c_ep = lane >> 3, i_ep = lane & 7;
  const int m_ = lane & 15, dg = lane >> 4;      // f'/scores lane decomposition
  const char* xhb = (const char*)xh;
  _Float16* g16w = &q16[w][0];                   // alias: 4 h x 64 d, stride 64

  // P-staging lane map (slab s: m = s*4+pm, f16 offset po within row)
  const int pm = lane >> 4;
  const int po = ((lane & 15) >> 1) * 8 + 4 * (lane & 1);

  // ---- X gathers for BOTH vertices (row = lane>>3, chunk c = lane&7) ----
  int nbA0 = nbr[(size_t)va * 16 + (lane >> 3)];
  int nbA1 = nbr[(size_t)va * 16 + 8 + (lane >> 3)];
  int nbB0 = nbr[(size_t)vb * 16 + (lane >> 3)];
  int nbB1 = nbr[(size_t)vb * 16 + 8 + (lane >> 3)];
  uint4 xA0 = *(const uint4*)(xhb + (size_t)nbA0 * 128 + (lane & 7) * 16);
  uint4 xA1 = *(const uint4*)(xhb + (size_t)nbA1 * 128 + (lane & 7) * 16);
  uint4 xB0 = *(const uint4*)(xhb + (size_t)nbB0 * 128 + (lane & 7) * 16);
  uint4 xB1 = *(const uint4*)(xhb + (size_t)nbB1 * 128 + (lane & 7) * 16);

  // ---- P loads for BOTH vertices, coalesced, plain-cached ----
  f32x4 a0, a1, a2, a3, b0, b1, b2, b3;
  {
    const f32x4* PgA = (const f32x4*)(P + (size_t)va * 1024);
    const f32x4* PgB = (const f32x4*)(P + (size_t)vb * 1024);
    a0 = PgA[lane];          // slab 0: flat lane*4
    a1 = PgA[64 + lane];     // slab 1
    a2 = PgA[128 + lane];    // slab 2
    a3 = PgA[192 + lane];    // slab 3
    b0 = PgB[lane];
    b1 = PgB[64 + lane];
    b2 = PgB[128 + lane];
    b3 = PgB[192 + lane];
  }

  // ---- stage Ph(va) (slab map), Xd(va) into stride-72 tiles ----
  {
    uint2 u0, u1, u2, u3;
    u0.x = pk2(a0[0], a0[1]); u0.y = pk2(a0[2], a0[3]);
    u1.x = pk2(a1[0], a1[1]); u1.y = pk2(a1[2], a1[3]);
    u2.x = pk2(a2[0], a2[1]); u2.y = pk2(a2[2], a2[3]);
    u3.x = pk2(a3[0], a3[1]); u3.y = pk2(a3[2], a3[3]);
    *(uint2*)&TA[w][(0 + pm) * 72 + po]  = u0;
    *(uint2*)&TA[w][(4 + pm) * 72 + po]  = u1;
    *(uint2*)&TA[w][(8 + pm) * 72 + po]  = u2;
    *(uint2*)&TA[w][(12 + pm) * 72 + po] = u3;
    *(uint4*)&TB[w][(lane >> 3) * 72 + (lane & 7) * 8] = xA0;
    *(uint4*)&TB[w][((lane >> 3) + 8) * 72 + (lane & 7) * 8] = xA1;
  }

  // ---- rbar ----
  float rbq[4];
#pragma unroll
  for (int tt = 0; tt < 4; ++tt) rbq[tt] = rbar[w * 64 + tt * 16 + (lane & 15)];

  // ---- q~ via ONE MFMA pass: A rows i = lane&15, vertex = v0 + (i&7); rows 8..15 dup ----
  {
    const int od0 = w * 64;
    uint4 bu[2][4];
#pragma unroll
    for (int s = 0; s < 2; ++s)
#pragma unroll
      for (int tt = 0; tt < 4; ++tt)
        bu[s][tt] = *(const uint4*)&AhTs[((s * 4 + (lane >> 4)) * 256 + od0 + tt * 16 + (lane & 15)) * 4];

    const uint4* xr = (const uint4*)(xh + (size_t)(v0 + (lane & 7)) * 32);
    f16x8 af0 = u4h8(xr[(lane >> 4)]);       // K-step 0: e 0..31 (octet kg)
    f16x8 af1 = u4h8(xr[4 + (lane >> 4)]);   // K-step 1: e 32..63
    f32x4 acc[4];
#pragma unroll
    for (int tt = 0; tt < 4; ++tt) acc[tt] = (f32x4){0.f, 0.f, 0.f, 0.f};
    __builtin_amdgcn_s_setprio(1);
#pragma unroll
    for (int tt = 0; tt < 4; ++tt)
#pragma unroll
      for (int s = 0; s < 2; ++s)
        acc[tt] = __builtin_amdgcn_mfma_f32_16x16x32_f16(s ? af1 : af0, u4h8(bu[s][tt]),
                                                         acc[tt], 0, 0, 0);
    __builtin_amdgcn_s_setprio(0);
    // C: col = lane&15, row = (lane>>4)*4 + reg; rows 0..7 = v0..v0+7 (lanes 0..31)
    if (lane < 32) {
#pragma unroll
      for (int tt = 0; tt < 4; ++tt)
#pragma unroll
        for (int reg = 0; reg < 4; ++reg)
          q16[(lane >> 4) * 4 + reg][od0 + tt * 16 + (lane & 15)] =
              (_Float16)(acc[tt][reg] + rbq[tt]);
    }
  }
  __syncthreads();   // drains VMEM + LDS (Ph/Xd(va), q16); publishes q16

  // ---- hoisted B-frags for both vertices + epilogue weights ----
  // (q16[w] becomes dead for this wave after these 4 reads -> reused as g16)
  const int hb = (lane & 15) & 3;
  f16x8 bqa0 = u4h8(*(const uint4*)&q16[w][hb * 64 + dg * 8]);
  f16x8 bqa1 = u4h8(*(const uint4*)&q16[w][hb * 64 + 32 + dg * 8]);
  f16x8 bqb0 = u4h8(*(const uint4*)&q16[4 + w][hb * 64 + dg * 8]);
  f16x8 bqb1 = u4h8(*(const uint4*)&q16[4 + w][hb * 64 + 32 + dg * 8]);
  uint4 wq[4];
#pragma unroll
  for (int h = 0; h < 4; ++h) wq[h] = *(const uint4*)&wvh[i_ep * 16 + h * 4];

  const int rl = lane & 15, kg = lane >> 4;

  // ================= vertex va : f' + scores + softmax =================
  uint4 A0a, A1a;
  f16x4 eba;
  {
    uint4 Plo = *(const uint4*)&TA[w][m_ * 72 + dg * 8];           // P[m_][o=dg][j]
    uint4 Phi = *(const uint4*)&TA[w][m_ * 72 + (dg + 4) * 8];     // P[m_][o=dg+4][j]
    float fr0[8], fr1[8];
    __builtin_amdgcn_s_setprio(1);
#pragma unroll
    for (int c = 0; c < 8; ++c) {
      uint4 Xu = *(const uint4*)&TB[w][m_ * 72 + c * 8];           // X[m_][c][j]
      fr0[c] = fdot2f(u2h(Plo.x), u2h(Xu.x),
               fdot2f(u2h(Plo.y), u2h(Xu.y),
               fdot2f(u2h(Plo.z), u2h(Xu.z),
               fdot2f(u2h(Plo.w), u2h(Xu.w), 0.f))));
      fr1[c] = fdot2f(u2h(Phi.x), u2h(Xu.x),
               fdot2f(u2h(Phi.y), u2h(Xu.y),
               fdot2f(u2h(Phi.z), u2h(Xu.z),
               fdot2f(u2h(Phi.w), u2h(Xu.w), 0.f))));
    }
    __builtin_amdgcn_s_setprio(0);
    A0a.x = pk2(fr0[0], fr0[1]); A0a.y = pk2(fr0[2], fr0[3]);
    A0a.z = pk2(fr0[4], fr0[5]); A0a.w = pk2(fr0[6], fr0[7]);
    A1a.x = pk2(fr1[0], fr1[1]); A1a.y = pk2(fr1[2], fr1[3]);
    A1a.z = pk2(fr1[4], fr1[5]); A1a.w = pk2(fr1[6], fr1[7]);
    f32x4 sac = (f32x4){0.f, 0.f, 0.f, 0.f};
    sac = __builtin_amdgcn_mfma_f32_16x16x32_f16(u4h8(A0a), bqa0, sac, 0, 0, 0);
    sac = __builtin_amdgcn_mfma_f32_16x16x32_f16(u4h8(A1a), bqa1, sac, 0, 0, 0);
    // in-register softmax
    float e0 = __expf(sac[0]), e1 = __expf(sac[1]);
    float e2 = __expf(sac[2]), e3 = __expf(sac[3]);
    float pp = (e0 + e1) + (e2 + e3);
    pp += __shfl_xor(pp, 16);
    pp += __shfl_xor(pp, 32);
    float is = __builtin_amdgcn_rcpf(pp);
    uint2 eu;
    eu.x = pk2(e0 * is, e1 * is);
    eu.y = pk2(e2 * is, e3 * is);
    eba = u2h4(eu);
  }
  lds_fence();   // f'(va) tile reads + bq hoists retired -> safe to overwrite TA/TB/TC/q16[w]

  // ---- epoch: Ftr(va)->TC ; Ph(vb)->TA ; Xd(vb)->TB ----
  *(uint4*)&TC[w][m_ * 72 + dg * 8] = A0a;          // F[m_][dg*8..+8]
  *(uint4*)&TC[w][m_ * 72 + 32 + dg * 8] = A1a;     // F[m_][32+dg*8..+8]
  {
    uint2 u0, u1, u2, u3;
    u0.x = pk2(b0[0], b0[1]); u0.y = pk2(b0[2], b0[3]);
    u1.x = pk2(b1[0], b1[1]); u1.y = pk2(b1[2], b1[3]);
    u2.x = pk2(b2[0], b2[1]); u2.y = pk2(b2[2], b2[3]);
    u3.x = pk2(b3[0], b3[1]); u3.y = pk2(b3[2], b3[3]);
    *(uint2*)&TA[w][(0 + pm) * 72 + po]  = u0;
    *(uint2*)&TA[w][(4 + pm) * 72 + po]  = u1;
    *(uint2*)&TA[w][(8 + pm) * 72 + po]  = u2;
    *(uint2*)&TA[w][(12 + pm) * 72 + po] = u3;
    *(uint4*)&TB[w][(lane >> 3) * 72 + (lane & 7) * 8] = xB0;
    *(uint4*)&TB[w][((lane >> 3) + 8) * 72 + (lane & 7) * 8] = xB1;
  }
  lds_fence();   // TC/TA/TB writes visible

  // ---- g(va) via MFMA ----
  __builtin_amdgcn_s_setprio(1);
#pragma unroll
  for (int b2i = 0; b2i < 4; ++b2i) {
    f16x4 ga;
#pragma unroll
    for (int tt = 0; tt < 4; ++tt)
      ga[tt] = TC[w][(kg * 4 + tt) * 72 + b2i * 16 + rl];   // A[i=rl][k=kg*4+tt]
    f32x4 zg = (f32x4){0.f, 0.f, 0.f, 0.f};
    f32x4 gacc = __builtin_amdgcn_mfma_f32_16x16x16f16(ga, eba, zg, 0, 0, 0);
    if (rl < 4) {
      uint2 gv;
      gv.x = pk2(gacc[0], gacc[1]);
      gv.y = pk2(gacc[2], gacc[3]);
      *(uint2*)&g16w[rl * 64 + b2i * 16 + kg * 4] = gv;
    }
  }
  __builtin_amdgcn_s_setprio(0);

  // ---- f'(vb) + scores(vb) + softmax(vb) (overlaps g(va) in same epoch) ----
  uint4 A0b, A1b;
  f16x4 ebb;
  {
    uint4 Plo = *(const uint4*)&TA[w][m_ * 72 + dg * 8];
    uint4 Phi = *(const uint4*)&TA[w][m_ * 72 + (dg + 4) * 8];
    float fr0[8], fr1[8];
    __builtin_amdgcn_s_setprio(1);
#pragma unroll
    for (int c = 0; c < 8; ++c) {
      uint4 Xu = *(const uint4*)&TB[w][m_ * 72 + c * 8];
      fr0[c] = fdot2f(u2h(Plo.x), u2h(Xu.x),
               fdot2f(u2h(Plo.y), u2h(Xu.y),
               fdot2f(u2h(Plo.z), u2h(Xu.z),
               fdot2f(u2h(Plo.w), u2h(Xu.w), 0.f))));
      fr1[c] = fdot2f(u2h(Phi.x), u2h(Xu.x),
               fdot2f(u2h(Phi.y), u2h(Xu.y),
               fdot2f(u2h(Phi.z), u2h(Xu.z),
               fdot2f(u2h(Phi.w), u2h(Xu.w), 0.f))));
    }
    __builtin_amdgcn_s_setprio(0);
    A0b.x = pk2(fr0[0], fr0[1]); A0b.y = pk2(fr0[2], fr0[3]);
    A0b.z = pk2(fr0[4], fr0[5]); A0b.w = pk2(fr0[6], fr0[7]);
    A1b.x = pk2(fr1[0], fr1[1]); A1b.y = pk2(fr1[2], fr1[3]);
    A1b.z = pk2(fr1[4], fr1[5]); A1b.w = pk2(fr1[6], fr1[7]);
    f32x4 sac = (f32x4){0.f, 0.f, 0.f, 0.f};
    sac = __builtin_amdgcn_mfma_f32_16x16x32_f16(u4h8(A0b), bqb0, sac, 0, 0, 0);
    sac = __builtin_amdgcn_mfma_f32_16x16x32_f16(u4h8(A1b), bqb1, sac, 0, 0, 0);
    float e0 = __expf(sac[0]), e1 = __expf(sac[1]);
    float e2 = __expf(sac[2]), e3 = __expf(sac[3]);
    float pp = (e0 + e1) + (e2 + e3);
    pp += __shfl_xor(pp, 16);
    pp += __shfl_xor(pp, 32);
    float is = __builtin_amdgcn_rcpf(pp);
    uint2 eu;
    eu.x = pk2(e0 * is, e1 * is);
    eu.y = pk2(e2 * is, e3 * is);
    ebb = u2h4(eu);
  }
  lds_fence();   // g16(va) writes visible; f'(vb)/ga(va) reads retired

  // ---- epilogue(va) + Ftr(vb)->TC (TC's va reads done) ----
#pragma unroll
  for (int h = 0; h < 4; ++h) {
    uint4 gq = *(const uint4*)&g16w[h * 64 + c_ep * 8];
    float oacc = fdot2f(u2h(wq[h].x), u2h(gq.x),
                 fdot2f(u2h(wq[h].y), u2h(gq.y),
                 fdot2f(u2h(wq[h].z), u2h(gq.z),
                 fdot2f(u2h(wq[h].w), u2h(gq.w), 0.f))));
    __builtin_nontemporal_store(oacc, &out[(size_t)va * 256 + h * 64 + lane]);
  }
  *(uint4*)&TC[w][m_ * 72 + dg * 8] = A0b;
  *(uint4*)&TC[w][m_ * 72 + 32 + dg * 8] = A1b;
  lds_fence();   // epi(va) g16 reads done; Ftr(vb) visible

  // ---- g(vb) ----
  __builtin_amdgcn_s_setprio(1);
#pragma unroll
  for (int b2i = 0; b2i < 4; ++b2i) {
    f16x4 ga;
#pragma unroll
    for (int tt = 0; tt < 4; ++tt)
      ga[tt] = TC[w][(kg * 4 + tt) * 72 + b2i * 16 + rl];
    f32x4 zg = (f32x4){0.f, 0.f, 0.f, 0.f};
    f32x4 gacc = __builtin_amdgcn_mfma_f32_16x16x16f16(ga, ebb, zg, 0, 0, 0);
    if (rl < 4) {
      uint2 gv;
      gv.x = pk2(gacc[0], gacc[1]);
      gv.y = pk2(gacc[2], gacc[3]);
      *(uint2*)&g16w[rl * 64 + b2i * 16 + kg * 4] = gv;
    }
  }
  __builtin_amdgcn_s_setprio(0);
  lds_fence();

  // ---- epilogue(vb) ----
#pragma unroll
  for (int h = 0; h < 4; ++h) {
    uint4 gq = *(const uint4*)&g16w[h * 64 + c_ep * 8];
    float oacc = fdot2f(u2h(wq[h].x), u2h(gq.x),
                 fdot2f(u2h(wq[h].y), u2h(gq.y),
                 fdot2f(u2h(wq[h].z), u2h(gq.z),
                 fdot2f(u2h(wq[h].w), u2h(gq.w), 0.f))));
    __builtin_nontemporal_store(oacc, &out[(size_t)vb * 256 + h * 64 + lane]);
  }
}

extern "C" void kernel_launch(void* const* d_in, const int* in_sizes, int n_in,
                              void* d_out, int out_size, void* d_ws, size_t ws_size,
                              hipStream_t stream) {
  const float* x      = (const float*)d_in[0];
  const int*   nbr    = (const int*)d_in[1];
  const float* P      = (const float*)d_in[2];
  // d_in[3] = rel_pos_u : unused by the reference
  const float* WQ     = (const float*)d_in[4];
  const float* WQb    = (const float*)d_in[5];
  const float* WK     = (const float*)d_in[6];
  // d_in[7] = W_K_b : softmax-invariant -> dropped
  const float* bases  = (const float*)d_in[8];
  const float* coeffs = (const float*)d_in[9];

  unsigned* AhTs = (unsigned*)d_ws;
  float* rbar   = (float*)((char*)d_ws + 32768);
  unsigned* wvh = (unsigned*)((char*)d_ws + 33792);
  unsigned* xh  = (unsigned*)((char*)d_ws + 34816);
  float* out    = (float*)d_out;

  hipLaunchKernelGGL(prep_kernel, dim3(32 + (NV * 8 + 255) / 256), dim3(256), 0, stream,
                     WQ, WQb, WK, bases, coeffs, x, AhTs, rbar, wvh, xh);
  hipLaunchKernelGGL(attn_kernel, dim3(NV / 8), dim3(256), 0, stream,
                     xh, nbr, P, AhTs, rbar, wvh, out);
}